// Round 1
// baseline (332.322 us; speedup 1.0000x reference)
//
#include <hip/hip_runtime.h>
#include <hip/hip_bf16.h>

// Problem: B=8, T=2048, D=1024, HS=128 causal attention head.
// d_in: x fp32 [8,2048,1024], Wq/Wk/Wv fp32 [1024,128]. d_out: fp32 [8,2048,128].
// d_ws: q,k,v bf16, 3 * 16384*128*2 = 12.6 MB.

typedef __bf16 bf16x8 __attribute__((ext_vector_type(8)));
typedef float floatx4 __attribute__((ext_vector_type(4)));

#define B_  8
#define T_  2048
#define D_  1024
#define HS_ 128
#define M_  (B_ * T_)   // 16384

// ---------------------------------------------------------------------------
// Kernel 1: QKV projection.  C[16384,128] = bf16(x)[16384,1024] * bf16(W)[1024,128]
// grid (M/64, 3), block 256 (4 waves). Each wave: 16 rows x 128 cols = 8 MFMA tiles.
// ---------------------------------------------------------------------------
__global__ __launch_bounds__(256) void qkv_proj(
    const float* __restrict__ x,
    const float* __restrict__ Wq, const float* __restrict__ Wk,
    const float* __restrict__ Wv,
    __hip_bfloat16* __restrict__ qkv)
{
    const int mt   = blockIdx.x;
    const int wsel = blockIdx.y;
    const float* W = (wsel == 0) ? Wq : ((wsel == 1) ? Wk : Wv);
    __hip_bfloat16* out = qkv + (size_t)wsel * M_ * HS_;

    __shared__ __hip_bfloat16 sA[64][72];    // [m][k], +8 pad breaks bank conflicts
    __shared__ __hip_bfloat16 sBt[128][72];  // [n][k] (transposed for B-frag reads)

    const int tid  = threadIdx.x;
    const int lane = tid & 63;
    const int w    = tid >> 6;   // wave 0..3
    const int quad = lane >> 4;
    const int l16  = lane & 15;

    floatx4 acc[8];
    #pragma unroll
    for (int i = 0; i < 8; ++i) acc[i] = (floatx4){0.f, 0.f, 0.f, 0.f};

    const int m0 = mt * 64;

    for (int kt = 0; kt < D_ / 64; ++kt) {
        const int k0 = kt * 64;
        // stage A tile: 64 rows x 64 cols fp32 -> bf16
        {
            const int r  = tid >> 4;   // 0..15
            const int c4 = tid & 15;   // float4 column
            #pragma unroll
            for (int rr = 0; rr < 4; ++rr) {
                const int row = r + rr * 16;
                const float4 vv = *(const float4*)(x + (size_t)(m0 + row) * D_ + k0 + c4 * 4);
                __hip_bfloat16* dst = &sA[row][c4 * 4];
                dst[0] = __float2bfloat16(vv.x);
                dst[1] = __float2bfloat16(vv.y);
                dst[2] = __float2bfloat16(vv.z);
                dst[3] = __float2bfloat16(vv.w);
            }
        }
        // stage B tile transposed: W[k0..k0+63][0..127] -> sBt[n][k]
        {
            const int kk = tid >> 5;   // 0..7
            const int c4 = tid & 31;   // float4 column (128 cols)
            #pragma unroll
            for (int kk2 = 0; kk2 < 8; ++kk2) {
                const int krow = kk + kk2 * 8;
                const float4 vv = *(const float4*)(W + (size_t)(k0 + krow) * HS_ + c4 * 4);
                sBt[c4 * 4 + 0][krow] = __float2bfloat16(vv.x);
                sBt[c4 * 4 + 1][krow] = __float2bfloat16(vv.y);
                sBt[c4 * 4 + 2][krow] = __float2bfloat16(vv.z);
                sBt[c4 * 4 + 3][krow] = __float2bfloat16(vv.w);
            }
        }
        __syncthreads();

        #pragma unroll
        for (int ks = 0; ks < 2; ++ks) {
            const bf16x8 a = *(const bf16x8*)&sA[w * 16 + l16][ks * 32 + quad * 8];
            #pragma unroll
            for (int c = 0; c < 8; ++c) {
                const bf16x8 b = *(const bf16x8*)&sBt[c * 16 + l16][ks * 32 + quad * 8];
                acc[c] = __builtin_amdgcn_mfma_f32_16x16x32_bf16(a, b, acc[c], 0, 0, 0);
            }
        }
        __syncthreads();
    }

    // C/D layout: row = quad*4 + r, col = l16 (verified m89/m91)
    #pragma unroll
    for (int c = 0; c < 8; ++c) {
        #pragma unroll
        for (int r = 0; r < 4; ++r) {
            const int row = m0 + w * 16 + quad * 4 + r;
            const int col = c * 16 + l16;
            out[(size_t)row * HS_ + col] = __float2bfloat16(acc[c][r]);
        }
    }
}

// ---------------------------------------------------------------------------
// Kernel 2: flash attention, causal. grid (T/64, B), block 256 (4 waves).
// Each block: 64 q-rows; each wave owns 16 q-rows. Iterate k/v tiles of 64.
// ---------------------------------------------------------------------------
__global__ __launch_bounds__(256) void attn(
    const __hip_bfloat16* __restrict__ qkv,
    float* __restrict__ out)
{
    const int qt = blockIdx.x;
    const int b  = blockIdx.y;
    const __hip_bfloat16* q = qkv;
    const __hip_bfloat16* k = qkv + (size_t)M_ * HS_;
    const __hip_bfloat16* v = qkv + (size_t)2 * M_ * HS_;

    __shared__ __hip_bfloat16 sK[64][136];    // [key][dim], pad to 136
    __shared__ __hip_bfloat16 sVt[128][72];   // [dim][key] transposed
    __shared__ __hip_bfloat16 sP[4][16][72];  // per-wave P round-trip buffer

    const int tid  = threadIdx.x;
    const int lane = tid & 63;
    const int w    = tid >> 6;
    const int quad = lane >> 4;
    const int l16  = lane & 15;

    const int t0 = qt * 64;
    const size_t brow = (size_t)b * T_;

    // Q fragments in registers: wave w rows t0 + w*16 + (0..15), A-layout
    bf16x8 aq[4];
    #pragma unroll
    for (int kt = 0; kt < 4; ++kt)
        aq[kt] = *(const bf16x8*)(q + (brow + t0 + w * 16 + l16) * HS_ + kt * 32 + quad * 8);

    floatx4 acc_o[8];
    #pragma unroll
    for (int i = 0; i < 8; ++i) acc_o[i] = (floatx4){0.f, 0.f, 0.f, 0.f};
    float m_i[4], l_i[4];
    #pragma unroll
    for (int r = 0; r < 4; ++r) { m_i[r] = -1e30f; l_i[r] = 0.0f; }

    const float scale = 0.08838834764831845f;  // 128^-0.5

    for (int st = 0; st <= qt; ++st) {
        const int s0 = st * 64;
        // stage K tile [64][128]
        {
            const int r  = tid >> 4;
            const int c8 = tid & 15;
            #pragma unroll
            for (int rr = 0; rr < 4; ++rr) {
                const int row = r + rr * 16;
                *(bf16x8*)&sK[row][c8 * 8] =
                    *(const bf16x8*)(k + (brow + s0 + row) * HS_ + c8 * 8);
            }
        }
        // stage V tile transposed -> sVt[dim][key]
        {
            const int r  = tid >> 4;
            const int c8 = tid & 15;
            #pragma unroll
            for (int rr = 0; rr < 4; ++rr) {
                const int row = r + rr * 16;  // key index
                const bf16x8 vv = *(const bf16x8*)(v + (brow + s0 + row) * HS_ + c8 * 8);
                #pragma unroll
                for (int j = 0; j < 8; ++j)
                    sVt[c8 * 8 + j][row] = ((const __hip_bfloat16*)&vv)[j];
            }
        }
        __syncthreads();

        // S = Q K^T : 16 q-rows x 64 keys per wave
        floatx4 acc_s[4];
        #pragma unroll
        for (int c = 0; c < 4; ++c) acc_s[c] = (floatx4){0.f, 0.f, 0.f, 0.f};
        #pragma unroll
        for (int kt = 0; kt < 4; ++kt) {
            #pragma unroll
            for (int c = 0; c < 4; ++c) {
                const bf16x8 bk = *(const bf16x8*)&sK[c * 16 + l16][kt * 32 + quad * 8];
                acc_s[c] = __builtin_amdgcn_mfma_f32_16x16x32_bf16(aq[kt], bk, acc_s[c], 0, 0, 0);
            }
        }

        // online softmax (rows = quad*4 + r within wave block)
        const bool diag = (st == qt);
        #pragma unroll
        for (int r = 0; r < 4; ++r) {
            float pr[4];
            float mx = -1e30f;
            #pragma unroll
            for (int c = 0; c < 4; ++c) {
                float sv = acc_s[c][r] * scale;
                if (diag) {
                    const int gcol = s0 + c * 16 + l16;
                    const int grow = t0 + w * 16 + quad * 4 + r;
                    if (gcol > grow) sv = -1e30f;
                }
                pr[c] = sv;
                mx = fmaxf(mx, sv);
            }
            #pragma unroll
            for (int off = 8; off >= 1; off >>= 1)
                mx = fmaxf(mx, __shfl_xor(mx, off, 64));
            const float mnew  = fmaxf(m_i[r], mx);
            const float alpha = __expf(m_i[r] - mnew);
            float rsum = 0.f;
            #pragma unroll
            for (int c = 0; c < 4; ++c) {
                const float pv = __expf(pr[c] - mnew);
                pr[c] = pv;
                rsum += pv;
            }
            #pragma unroll
            for (int off = 8; off >= 1; off >>= 1)
                rsum += __shfl_xor(rsum, off, 64);
            l_i[r] = l_i[r] * alpha + rsum;
            m_i[r] = mnew;
            #pragma unroll
            for (int c = 0; c < 8; ++c) acc_o[c][r] *= alpha;
            #pragma unroll
            for (int c = 0; c < 4; ++c)
                sP[w][quad * 4 + r][c * 16 + l16] = __float2bfloat16(pr[c]);
        }
        __syncthreads();

        // O += P V : P in A-layout from sP, V from sVt
        #pragma unroll
        for (int ss = 0; ss < 2; ++ss) {
            const bf16x8 ap = *(const bf16x8*)&sP[w][l16][ss * 32 + quad * 8];
            #pragma unroll
            for (int c = 0; c < 8; ++c) {
                const bf16x8 bv = *(const bf16x8*)&sVt[c * 16 + l16][ss * 32 + quad * 8];
                acc_o[c] = __builtin_amdgcn_mfma_f32_16x16x32_bf16(ap, bv, acc_o[c], 0, 0, 0);
            }
        }
        __syncthreads();
    }

    // epilogue: normalize by l and write fp32
    #pragma unroll
    for (int c = 0; c < 8; ++c) {
        #pragma unroll
        for (int r = 0; r < 4; ++r) {
            const int row = t0 + w * 16 + quad * 4 + r;
            const float o = acc_o[c][r] / l_i[r];
            out[(brow + row) * HS_ + c * 16 + l16] = o;
        }
    }
}

extern "C" void kernel_launch(void* const* d_in, const int* in_sizes, int n_in,
                              void* d_out, int out_size, void* d_ws, size_t ws_size,
                              hipStream_t stream) {
    const float* x  = (const float*)d_in[0];
    const float* Wq = (const float*)d_in[1];
    const float* Wk = (const float*)d_in[2];
    const float* Wv = (const float*)d_in[3];
    float* out = (float*)d_out;
    __hip_bfloat16* qkv = (__hip_bfloat16*)d_ws;   // 12.6 MB of ws

    qkv_proj<<<dim3(M_ / 64, 3), 256, 0, stream>>>(x, Wq, Wk, Wv, qkv);
    attn<<<dim3(T_ / 64, B_), 256, 0, stream>>>(qkv, out);
}

// Round 2
// 208.249 us; speedup vs baseline: 1.5958x; 1.5958x over previous
//
#include <hip/hip_runtime.h>
#include <hip/hip_bf16.h>

// B=8, T=2048, D=1024, HS=128 causal attention head.
// Pipeline: wprep (W -> Wt bf16) ; qkv_gemm (Q,K natural bf16, V transposed bf16)
//           attn (2-way key-split flash, partials to ws) ; merge.

typedef __bf16 bf16x8 __attribute__((ext_vector_type(8)));
typedef __bf16 bf16x4 __attribute__((ext_vector_type(4)));
typedef float floatx4 __attribute__((ext_vector_type(4)));

#define B_  8
#define T_  2048
#define D_  1024
#define HS_ 128
#define M_  (B_ * T_)   // 16384

// ws byte offsets
#define OFF_Q   0u
#define OFF_K   4194304u           // 16384*128*2
#define OFF_VT  8388608u
#define OFF_WT  12582912u          // 3*128*1024*2 = 786432
#define OFF_OP  13369344u          // 2*16384*128*4 = 16777216
#define OFF_MP  30146560u          // 2*16384*4
#define OFF_LP  30277632u          // total end ~30.4 MB

// ---------------------------------------------------------------------------
// W[1024,128] fp32 -> Wt[128,1024] bf16 (x3). Coalesced writes, strided reads.
// ---------------------------------------------------------------------------
__global__ void wprep(const float* __restrict__ Wq, const float* __restrict__ Wk,
                      const float* __restrict__ Wv, __hip_bfloat16* __restrict__ Wt)
{
    const int idx  = blockIdx.x * 256 + threadIdx.x;     // grid 1536 -> 393216
    const int wsel = idx >> 17;
    const int rem  = idx & 131071;
    const int n    = rem >> 10;
    const int kk   = rem & 1023;
    const float* W = (wsel == 0) ? Wq : ((wsel == 1) ? Wk : Wv);
    Wt[idx] = __float2bfloat16(W[kk * HS_ + n]);
}

// ---------------------------------------------------------------------------
// QKV GEMM: C[16384,128] = bf16(x)[16384,1024] * Wt^T. Tile 128x128, BK=64.
// grid (128, 3), 256 threads (4 waves, each 64x64). V written transposed.
// ---------------------------------------------------------------------------
__global__ __launch_bounds__(256) void qkv_gemm(
    const float* __restrict__ x, const __hip_bfloat16* __restrict__ Wt_all,
    __hip_bfloat16* __restrict__ qg, __hip_bfloat16* __restrict__ kg,
    __hip_bfloat16* __restrict__ vtg)
{
    const int mt   = blockIdx.x;
    const int wsel = blockIdx.y;
    const __hip_bfloat16* Wt = Wt_all + (size_t)wsel * HS_ * D_;

    __shared__ __hip_bfloat16 sA[128][72];   // [m][k], pad 8 (row stride 144B -> spread banks)
    __shared__ __hip_bfloat16 sB[128][72];   // [n][k]

    const int tid  = threadIdx.x;
    const int lane = tid & 63;
    const int w    = tid >> 6;
    const int quad = lane >> 4;
    const int l16  = lane & 15;
    const int wrow = (w & 1) * 64;
    const int wcol = (w >> 1) * 64;
    const int m0   = mt * 128;

    floatx4 acc[4][4];
    #pragma unroll
    for (int i = 0; i < 4; ++i)
        #pragma unroll
        for (int j = 0; j < 4; ++j) acc[i][j] = (floatx4){0.f, 0.f, 0.f, 0.f};

    const int srow = tid >> 1;      // 0..127
    const int sseg = tid & 1;       // 32-col half

    for (int kt = 0; kt < D_ / 64; ++kt) {
        const int k0 = kt * 64;
        // stage A (fp32 -> bf16, vectorized)
        const float* asrc = x + (size_t)(m0 + srow) * D_ + k0 + sseg * 32;
        #pragma unroll
        for (int jj = 0; jj < 4; ++jj) {
            const float4 f0 = *(const float4*)(asrc + jj * 8);
            const float4 f1 = *(const float4*)(asrc + jj * 8 + 4);
            union { bf16x8 v; __hip_bfloat16 h[8]; } u;
            u.h[0] = __float2bfloat16(f0.x); u.h[1] = __float2bfloat16(f0.y);
            u.h[2] = __float2bfloat16(f0.z); u.h[3] = __float2bfloat16(f0.w);
            u.h[4] = __float2bfloat16(f1.x); u.h[5] = __float2bfloat16(f1.y);
            u.h[6] = __float2bfloat16(f1.z); u.h[7] = __float2bfloat16(f1.w);
            *(bf16x8*)&sA[srow][sseg * 32 + jj * 8] = u.v;
        }
        // stage B (already bf16, already [n][k])
        const __hip_bfloat16* bsrc = Wt + (size_t)srow * D_ + k0 + sseg * 32;
        #pragma unroll
        for (int jj = 0; jj < 4; ++jj)
            *(bf16x8*)&sB[srow][sseg * 32 + jj * 8] = *(const bf16x8*)(bsrc + jj * 8);
        __syncthreads();

        #pragma unroll
        for (int ks = 0; ks < 2; ++ks) {
            bf16x8 af[4], bf[4];
            #pragma unroll
            for (int i = 0; i < 4; ++i)
                af[i] = *(const bf16x8*)&sA[wrow + i * 16 + l16][ks * 32 + quad * 8];
            #pragma unroll
            for (int j = 0; j < 4; ++j)
                bf[j] = *(const bf16x8*)&sB[wcol + j * 16 + l16][ks * 32 + quad * 8];
            #pragma unroll
            for (int i = 0; i < 4; ++i)
                #pragma unroll
                for (int j = 0; j < 4; ++j)
                    acc[i][j] = __builtin_amdgcn_mfma_f32_16x16x32_bf16(af[i], bf[j], acc[i][j], 0, 0, 0);
        }
        __syncthreads();
    }

    // epilogue. C layout: row = quad*4+r, col = l16.
    if (wsel < 2) {
        __hip_bfloat16* out = wsel ? kg : qg;
        #pragma unroll
        for (int i = 0; i < 4; ++i)
            #pragma unroll
            for (int j = 0; j < 4; ++j)
                #pragma unroll
                for (int r = 0; r < 4; ++r)
                    out[(size_t)(m0 + wrow + i * 16 + quad * 4 + r) * HS_ + wcol + j * 16 + l16] =
                        __float2bfloat16(acc[i][j][r]);
    } else {
        // V transposed: vt[b][h][t]
        #pragma unroll
        for (int i = 0; i < 4; ++i) {
            const int row0 = m0 + wrow + i * 16 + quad * 4;
            const int bb = row0 >> 11;
            const int t  = row0 & 2047;
            #pragma unroll
            for (int j = 0; j < 4; ++j) {
                const int col = wcol + j * 16 + l16;
                union { bf16x4 v; __hip_bfloat16 h[4]; } u;
                #pragma unroll
                for (int r = 0; r < 4; ++r) u.h[r] = __float2bfloat16(acc[i][j][r]);
                *(bf16x4*)&vtg[(size_t)bb * HS_ * T_ + (size_t)col * T_ + t] = u.v;
            }
        }
    }
}

// ---------------------------------------------------------------------------
// Flash attention with 2-way key split. grid (2, 32, 8) = (split, qt rev, b).
// Block: 64 q-rows, 4 waves x 16 rows. Writes unnormalized O + (m,l) partials.
// ---------------------------------------------------------------------------
__global__ __launch_bounds__(256) void attn(
    const __hip_bfloat16* __restrict__ qg, const __hip_bfloat16* __restrict__ kg,
    const __hip_bfloat16* __restrict__ vtg,
    float* __restrict__ Opart, float* __restrict__ mpart, float* __restrict__ lpart)
{
    const int s  = blockIdx.x;
    const int qt = 31 - blockIdx.y;   // longest blocks dispatched first
    const int b  = blockIdx.z;

    __shared__ __hip_bfloat16 sK[64][136];
    __shared__ __hip_bfloat16 sVt[128][72];
    __shared__ __hip_bfloat16 sP[4][16][72];

    const int tid  = threadIdx.x;
    const int lane = tid & 63;
    const int w    = tid >> 6;
    const int quad = lane >> 4;
    const int l16  = lane & 15;

    const int t0 = qt * 64;
    const size_t brow = (size_t)b * T_;
    const __hip_bfloat16* vt_b = vtg + (size_t)b * HS_ * T_;

    bf16x8 aq[4];
    #pragma unroll
    for (int kt = 0; kt < 4; ++kt)
        aq[kt] = *(const bf16x8*)(qg + (brow + t0 + w * 16 + l16) * HS_ + kt * 32 + quad * 8);

    floatx4 acc_o[8];
    #pragma unroll
    for (int i = 0; i < 8; ++i) acc_o[i] = (floatx4){0.f, 0.f, 0.f, 0.f};
    float m_i[4], l_i[4];
    #pragma unroll
    for (int r = 0; r < 4; ++r) { m_i[r] = -1e30f; l_i[r] = 0.0f; }

    const float scale = 0.08838834764831845f;

    const int nt = qt + 1;
    const int n0 = (nt + 1) >> 1;
    const int st_begin = s ? n0 : 0;
    const int st_end   = s ? nt : n0;

    const int krow = tid >> 2, kseg = tid & 3;   // K: 64 rows x 4 segs of 32
    const int vrow = tid >> 1, vseg = tid & 1;   // Vt: 128 dims x 2 segs of 32

    for (int st = st_begin; st < st_end; ++st) {
        const int s0 = st * 64;
        const __hip_bfloat16* ksrc = kg + (brow + s0 + krow) * HS_ + kseg * 32;
        #pragma unroll
        for (int jj = 0; jj < 4; ++jj)
            *(bf16x8*)&sK[krow][kseg * 32 + jj * 8] = *(const bf16x8*)(ksrc + jj * 8);
        const __hip_bfloat16* vsrc = vt_b + (size_t)vrow * T_ + s0 + vseg * 32;
        #pragma unroll
        for (int jj = 0; jj < 4; ++jj)
            *(bf16x8*)&sVt[vrow][vseg * 32 + jj * 8] = *(const bf16x8*)(vsrc + jj * 8);
        __syncthreads();

        // S = Q K^T
        floatx4 acc_s[4];
        #pragma unroll
        for (int c = 0; c < 4; ++c) acc_s[c] = (floatx4){0.f, 0.f, 0.f, 0.f};
        #pragma unroll
        for (int kt = 0; kt < 4; ++kt)
            #pragma unroll
            for (int c = 0; c < 4; ++c) {
                const bf16x8 bk = *(const bf16x8*)&sK[c * 16 + l16][kt * 32 + quad * 8];
                acc_s[c] = __builtin_amdgcn_mfma_f32_16x16x32_bf16(aq[kt], bk, acc_s[c], 0, 0, 0);
            }

        // online softmax
        const bool diag = (st == qt);
        #pragma unroll
        for (int r = 0; r < 4; ++r) {
            float pr[4];
            float mx = -1e30f;
            #pragma unroll
            for (int c = 0; c < 4; ++c) {
                float sv = acc_s[c][r] * scale;
                if (diag) {
                    const int gcol = s0 + c * 16 + l16;
                    const int grow = t0 + w * 16 + quad * 4 + r;
                    if (gcol > grow) sv = -1e30f;
                }
                pr[c] = sv;
                mx = fmaxf(mx, sv);
            }
            #pragma unroll
            for (int off = 8; off >= 1; off >>= 1)
                mx = fmaxf(mx, __shfl_xor(mx, off, 64));
            const float mnew  = fmaxf(m_i[r], mx);
            const float alpha = __expf(m_i[r] - mnew);
            float rsum = 0.f;
            #pragma unroll
            for (int c = 0; c < 4; ++c) {
                const float pv = __expf(pr[c] - mnew);
                pr[c] = pv;
                rsum += pv;
            }
            #pragma unroll
            for (int off = 8; off >= 1; off >>= 1)
                rsum += __shfl_xor(rsum, off, 64);
            l_i[r] = l_i[r] * alpha + rsum;
            m_i[r] = mnew;
            #pragma unroll
            for (int c = 0; c < 8; ++c) acc_o[c][r] *= alpha;
            #pragma unroll
            for (int c = 0; c < 4; ++c)
                sP[w][quad * 4 + r][c * 16 + l16] = __float2bfloat16(pr[c]);
        }
        // NO barrier: sP is wave-private; sVt reads race nothing until end barrier.

        #pragma unroll
        for (int ss = 0; ss < 2; ++ss) {
            const bf16x8 ap = *(const bf16x8*)&sP[w][l16][ss * 32 + quad * 8];
            #pragma unroll
            for (int c = 0; c < 8; ++c) {
                const bf16x8 bv = *(const bf16x8*)&sVt[c * 16 + l16][ss * 32 + quad * 8];
                acc_o[c] = __builtin_amdgcn_mfma_f32_16x16x32_bf16(ap, bv, acc_o[c], 0, 0, 0);
            }
        }
        __syncthreads();   // protect sK/sVt before next stage
    }

    // partial epilogue (unnormalized O, plus m and l)
    float* op = Opart + (size_t)s * M_ * HS_;
    #pragma unroll
    for (int c = 0; c < 8; ++c)
        #pragma unroll
        for (int r = 0; r < 4; ++r) {
            const int row = t0 + w * 16 + quad * 4 + r;
            op[(brow + row) * HS_ + c * 16 + l16] = acc_o[c][r];
        }
    if (l16 == 0) {
        #pragma unroll
        for (int r = 0; r < 4; ++r) {
            const int row = t0 + w * 16 + quad * 4 + r;
            mpart[s * M_ + brow + row] = m_i[r];
            lpart[s * M_ + brow + row] = l_i[r];
        }
    }
}

// ---------------------------------------------------------------------------
// Merge the two key-split partials. grid 1024 x 256 -> one thread per 8 cols.
// ---------------------------------------------------------------------------
__global__ void merge(const float* __restrict__ Opart, const float* __restrict__ mpart,
                      const float* __restrict__ lpart, float* __restrict__ out)
{
    const int idx = blockIdx.x * 256 + threadIdx.x;   // 262144
    const int row = idx >> 4;
    const int c8  = (idx & 15) * 8;
    const float m0v = mpart[row],      m1v = mpart[M_ + row];
    const float l0v = lpart[row],      l1v = lpart[M_ + row];
    const float m   = fmaxf(m0v, m1v);
    const float a0  = __expf(m0v - m), a1 = __expf(m1v - m);
    const float inv = 1.0f / (a0 * l0v + a1 * l1v);
    const float4 o0a = *(const float4*)(Opart + (size_t)row * HS_ + c8);
    const float4 o0b = *(const float4*)(Opart + (size_t)row * HS_ + c8 + 4);
    const float4 o1a = *(const float4*)(Opart + (size_t)M_ * HS_ + (size_t)row * HS_ + c8);
    const float4 o1b = *(const float4*)(Opart + (size_t)M_ * HS_ + (size_t)row * HS_ + c8 + 4);
    float4 ra, rb;
    ra.x = (a0 * o0a.x + a1 * o1a.x) * inv; ra.y = (a0 * o0a.y + a1 * o1a.y) * inv;
    ra.z = (a0 * o0a.z + a1 * o1a.z) * inv; ra.w = (a0 * o0a.w + a1 * o1a.w) * inv;
    rb.x = (a0 * o0b.x + a1 * o1b.x) * inv; rb.y = (a0 * o0b.y + a1 * o1b.y) * inv;
    rb.z = (a0 * o0b.z + a1 * o1b.z) * inv; rb.w = (a0 * o0b.w + a1 * o1b.w) * inv;
    *(float4*)(out + (size_t)row * HS_ + c8)     = ra;
    *(float4*)(out + (size_t)row * HS_ + c8 + 4) = rb;
}

extern "C" void kernel_launch(void* const* d_in, const int* in_sizes, int n_in,
                              void* d_out, int out_size, void* d_ws, size_t ws_size,
                              hipStream_t stream) {
    const float* x  = (const float*)d_in[0];
    const float* Wq = (const float*)d_in[1];
    const float* Wk = (const float*)d_in[2];
    const float* Wv = (const float*)d_in[3];
    char* ws = (char*)d_ws;

    __hip_bfloat16* qg  = (__hip_bfloat16*)(ws + OFF_Q);
    __hip_bfloat16* kg  = (__hip_bfloat16*)(ws + OFF_K);
    __hip_bfloat16* vtg = (__hip_bfloat16*)(ws + OFF_VT);
    __hip_bfloat16* Wt  = (__hip_bfloat16*)(ws + OFF_WT);
    float* Opart = (float*)(ws + OFF_OP);
    float* mpart = (float*)(ws + OFF_MP);
    float* lpart = (float*)(ws + OFF_LP);

    wprep<<<1536, 256, 0, stream>>>(Wq, Wk, Wv, Wt);
    qkv_gemm<<<dim3(128, 3), 256, 0, stream>>>(x, Wt, qg, kg, vtg);
    attn<<<dim3(2, 32, 8), 256, 0, stream>>>(qg, kg, vtg, Opart, mpart, lpart);
    merge<<<1024, 256, 0, stream>>>(Opart, mpart, lpart, (float*)d_out);
}